// Round 1
// baseline (1144.113 us; speedup 1.0000x reference)
//
#include <hip/hip_runtime.h>

// NLBlockND non-local block, fp16-MFMA implementation (fp16 chosen over bf16:
// scores sigma~22.6 make softmax precision-critical; fp16's 2^-11 roundoff
// keeps score jitter ~0.01 vs bf16's ~0.1).
// Pipeline: cvt weights -> transpose x1/x2 to fp16 (B*N,C) -> 3 proj GEMMs
// (g stored transposed) -> flash attention (online softmax) -> wz GEMM +
// BN stats atomics -> BN finalize -> normalize+residual+transpose out.
//
// attn v2: raw s_barrier + lgkmcnt-only fences (keeps global prefetch in
// flight across barriers), disjoint PH/GX LDS buffers with T14 async-stage
// split (issue-early / write-late), wave-parallel softmax via shfl_xor
// (no serial sj==0 reductions), exp2-domain softmax, setprio around MFMA,
// rescale-skip when row max unchanged. 3 barriers/step instead of 6.

typedef _Float16 half8 __attribute__((ext_vector_type(8)));
typedef float floatx4 __attribute__((ext_vector_type(4)));

constexpr int B_ = 8, C_ = 1024, CI_ = 512, N_ = 3136;
constexpr int M_ = B_ * N_;            // 25088 rows (batch-major, n within batch)
constexpr float BN_EPS = 1e-5f;

// workspace layout (bytes, all 256-aligned)
constexpr size_t XT1_OFF = 0;
constexpr size_t XT2_OFF = XT1_OFF + (size_t)M_ * C_ * 2;
constexpr size_t WTH_OFF = XT2_OFF + (size_t)M_ * C_ * 2;
constexpr size_t WPH_OFF = WTH_OFF + (size_t)CI_ * C_ * 2;
constexpr size_t WG_OFF  = WPH_OFF + (size_t)CI_ * C_ * 2;
constexpr size_t WZB_OFF = WG_OFF  + (size_t)CI_ * C_ * 2;
constexpr size_t TH_OFF  = WZB_OFF + (size_t)C_ * CI_ * 2;
constexpr size_t PH_OFF  = TH_OFF  + (size_t)M_ * CI_ * 2;
constexpr size_t GXT_OFF = PH_OFF  + (size_t)M_ * CI_ * 2;
constexpr size_t Y_OFF   = GXT_OFF + (size_t)M_ * CI_ * 2;
constexpr size_t WY_OFF  = Y_OFF   + (size_t)M_ * CI_ * 2;   // fp16 wy
constexpr size_t SSUM_OFF= WY_OFF  + (size_t)M_ * C_ * 2;
constexpr size_t SSQ_OFF = SSUM_OFF + 4096;
constexpr size_t SC_OFF  = SSQ_OFF + 4096;                    // scale[1024], shift[1024]

__device__ __forceinline__ ushort f2h(float f) {
    _Float16 h = (_Float16)f;
    union { _Float16 h; ushort u; } v; v.h = h;
    return v.u;
}
__device__ __forceinline__ float h2f(ushort u) {
    union { ushort u; _Float16 h; } v; v.u = u;
    return (float)v.h;
}

// raw barrier: waits only LDS ops (lgkmcnt), leaves global prefetch (vmcnt)
// in flight — unlike __syncthreads(), which drains vmcnt(0) and serializes
// the staging latency into every phase.
__device__ __forceinline__ void bar_lgkm() {
    asm volatile("s_waitcnt lgkmcnt(0)" ::: "memory");
    __builtin_amdgcn_s_barrier();
}

// ---- weight convert: 4 arrays of 524288 floats -> fp16 -------------------
__global__ __launch_bounds__(256) void cvtw4(const float* __restrict__ a, const float* __restrict__ b,
                                             const float* __restrict__ c, const float* __restrict__ d,
                                             ushort* oa, ushort* ob, ushort* oc, ushort* od) {
    const float* s; ushort* o;
    switch (blockIdx.y) {
        case 0: s = a; o = oa; break;
        case 1: s = b; o = ob; break;
        case 2: s = c; o = oc; break;
        default: s = d; o = od; break;
    }
    int i = (blockIdx.x * 256 + threadIdx.x) * 4;
    float4 v = *(const float4*)&s[i];
    ushort4 u; u.x = f2h(v.x); u.y = f2h(v.y); u.z = f2h(v.z); u.w = f2h(v.w);
    *(ushort4*)&o[i] = u;
}

// ---- transpose x (B,C,N) fp32 -> xt (B*N, C) fp16 ------------------------
__global__ __launch_bounds__(256) void xpose(const float* __restrict__ x, ushort* __restrict__ xt) {
    __shared__ ushort T[64 * 68];
    const int b = blockIdx.z, n0 = blockIdx.y * 64, c0 = blockIdx.x * 64;
    const int t = threadIdx.x;
    {
        const int cl = t >> 4, jb = (t & 15) * 4;
        #pragma unroll
        for (int i = 0; i < 4; ++i) {
            int c = cl + i * 16;
            float4 v = *(const float4*)&x[((size_t)b * C_ + c0 + c) * N_ + n0 + jb];
            ushort4 u; u.x = f2h(v.x); u.y = f2h(v.y); u.z = f2h(v.z); u.w = f2h(v.w);
            *(ushort4*)&T[c * 68 + jb] = u;
        }
    }
    __syncthreads();
    {
        const int nl = t >> 4, cb = (t & 15) * 4;
        #pragma unroll
        for (int i = 0; i < 4; ++i) {
            int n = nl + i * 16;
            ushort4 u;
            u.x = T[(cb + 0) * 68 + n];
            u.y = T[(cb + 1) * 68 + n];
            u.z = T[(cb + 2) * 68 + n];
            u.w = T[(cb + 3) * 68 + n];
            *(ushort4*)&xt[((size_t)b * N_ + n0 + n) * C_ + c0 + cb] = u;
        }
    }
}

// ---- generic 128x128 fp16 MFMA GEMM: out = A(MxK) * Bt(NOUTxK)^T + bias --
// MODE 0: fp16 out row-major (stride NOUT)
// MODE 1: fp16 out transposed per-batch: GXT[b][col][n]  (NOUT==CI_)
// MODE 2: fp16 out row-major + per-col sum/sumsq atomics (BN stats)
template<int K, int NOUT, int MODE>
__global__ __launch_bounds__(256, 2) void gemm_bt(
    const ushort* __restrict__ A, const ushort* __restrict__ Bt,
    const float* __restrict__ bias, ushort* __restrict__ outb,
    float* __restrict__ ssum, float* __restrict__ ssq)
{
    __shared__ ushort Als[128 * 40];
    __shared__ ushort Bls[128 * 40];
    const int t = threadIdx.x;
    const int w = t >> 6, l = t & 63, quad = l >> 4, lid = l & 15;
    const int rw = w & 1, cw = w >> 1;
    const int rowbase = blockIdx.y * 128, colbase = blockIdx.x * 128;

    floatx4 acc[4][4] = {};

    for (int ks = 0; ks < K / 32; ++ks) {
        __syncthreads();
        #pragma unroll
        for (int i = 0; i < 2; ++i) {
            int idx = t + i * 256;
            int row = idx >> 2, ch = idx & 3;
            *(uint4*)&Als[row * 40 + ch * 8] =
                *(const uint4*)&A[(size_t)(rowbase + row) * K + ks * 32 + ch * 8];
            *(uint4*)&Bls[row * 40 + ch * 8] =
                *(const uint4*)&Bt[(size_t)(colbase + row) * K + ks * 32 + ch * 8];
        }
        __syncthreads();
        half8 af[4];
        #pragma unroll
        for (int rt = 0; rt < 4; ++rt)
            af[rt] = *(const half8*)&Als[(rw * 64 + rt * 16 + lid) * 40 + quad * 8];
        #pragma unroll
        for (int ct = 0; ct < 4; ++ct) {
            half8 bf = *(const half8*)&Bls[(cw * 64 + ct * 16 + lid) * 40 + quad * 8];
            #pragma unroll
            for (int rt = 0; rt < 4; ++rt)
                acc[rt][ct] = __builtin_amdgcn_mfma_f32_16x16x32_f16(af[rt], bf, acc[rt][ct], 0, 0, 0);
        }
    }

    #pragma unroll
    for (int ct = 0; ct < 4; ++ct) {
        const int col = colbase + cw * 64 + ct * 16 + lid;
        const float bv = bias[col];
        float s = 0.f, q = 0.f;
        #pragma unroll
        for (int rt = 0; rt < 4; ++rt) {
            const int row0 = rowbase + rw * 64 + rt * 16 + quad * 4;
            if constexpr (MODE == 1) {
                const int bb = row0 / N_;
                const int nn = row0 - bb * N_;
                ushort4 u;
                u.x = f2h(acc[rt][ct][0] + bv);
                u.y = f2h(acc[rt][ct][1] + bv);
                u.z = f2h(acc[rt][ct][2] + bv);
                u.w = f2h(acc[rt][ct][3] + bv);
                *(ushort4*)&outb[((size_t)bb * CI_ + col) * N_ + nn] = u;
            } else {
                #pragma unroll
                for (int r = 0; r < 4; ++r) {
                    float v = acc[rt][ct][r] + bv;
                    outb[(size_t)(row0 + r) * NOUT + col] = f2h(v);
                    if constexpr (MODE == 2) { s += v; q += v * v; }
                }
            }
        }
        if constexpr (MODE == 2) {
            s += __shfl_xor(s, 16, 64); s += __shfl_xor(s, 32, 64);
            q += __shfl_xor(q, 16, 64); q += __shfl_xor(q, 32, 64);
            if (quad == 0) {
                atomicAdd(&ssum[col], s);
                atomicAdd(&ssq[col], q);
            }
        }
    }
}

// ---- flash attention: per block one (batch, 64-row q-tile) ---------------
// TH fragments register-cached; PH and GX^T in disjoint single LDS buffers,
// staged via reg-prefetch issued 1.5 phases early (T14). Raw barriers keep
// prefetch loads in flight. Softmax in exp2 domain, wave-parallel via shfl.
__global__ __launch_bounds__(512, 2) void attn(
    const ushort* __restrict__ TH, const ushort* __restrict__ PH,
    const ushort* __restrict__ GXT, ushort* __restrict__ Y)
{
    __shared__ __align__(16) ushort PHb[32 * 520];   // PH tile  [32 kv][512 k]  (+8 pad)
    __shared__ __align__(16) ushort GXb[512 * 40];   // GX^T tile [512 d][32 kv] (+8 pad)
    __shared__ __align__(16) float  Ss[64 * 36];     // scores*log2e; stride 36: 2-way write, aligned f4 read
    __shared__ __align__(16) ushort Ps[64 * 40];     // P tile fp16
    __shared__ float mrow[64], lrow[64], arow[64];

    const int t = threadIdx.x;
    const int w = t >> 6, l = t & 63, quad = l >> 4, lid = l & 15;
    const int rw = w & 3;                  // row group (16 rows) for S and O
    const int dh = w >> 2;                 // d half (256 cols) for O
    const int b = blockIdx.x / 49, q = blockIdx.x % 49;
    const int n0 = q * 64;
    const int srow = t >> 3, sj = t & 7;   // softmax: 8 threads per row

    const size_t basePH_b = (size_t)b * N_ * CI_;
    const size_t baseGX_b = (size_t)b * CI_ * N_;

    // register-cache TH rows for this wave: rows n0 + rw*16 + lid, all 512 k
    half8 thr[16];
    {
        const size_t baseTH = ((size_t)b * N_ + n0 + rw * 16 + lid) * CI_;
        #pragma unroll
        for (int kc = 0; kc < 16; ++kc)
            thr[kc] = *(const half8*)&TH[baseTH + kc * 32 + quad * 8];
    }
    if (t < 64) { mrow[t] = -1e30f; lrow[t] = 0.f; arow[t] = 1.f; }

    // prologue: stage PH[0] to LDS; issue GX[0] prefetch (left in flight)
    uint4 phr[4], gxr[4];
    #pragma unroll
    for (int i = 0; i < 4; ++i) {
        int idx = t + i * 512;
        phr[i] = *(const uint4*)&PH[basePH_b + (size_t)(idx >> 6) * CI_ + (idx & 63) * 8];
    }
    #pragma unroll
    for (int i = 0; i < 4; ++i) {
        int idx = t + i * 512;
        gxr[i] = *(const uint4*)&GXT[baseGX_b + (size_t)(idx >> 2) * N_ + (idx & 3) * 8];
    }
    #pragma unroll
    for (int i = 0; i < 4; ++i) {
        int idx = t + i * 512;
        *(uint4*)&PHb[(idx >> 6) * 520 + (idx & 63) * 8] = phr[i];
    }
    bar_lgkm();                                    // B0: PHb[0] + m/l init visible

    floatx4 acc[16] = {};

    for (int s = 0; s < 98; ++s) {
        const int m0n = (s + 1) * 32;              // next kv-tile base

        // ---- phase 1: issue PH[s+1]; S = TH*PH^T; write Ss; write GXb[s] --
        if (s < 97) {
            #pragma unroll
            for (int i = 0; i < 4; ++i) {
                int idx = t + i * 512;
                phr[i] = *(const uint4*)&PH[basePH_b + (size_t)(m0n + (idx >> 6)) * CI_ + (idx & 63) * 8];
            }
        }
        {
            floatx4 sacc = {};
            __builtin_amdgcn_s_setprio(1);
            #pragma unroll
            for (int ks = 0; ks < 16; ++ks) {
                half8 bb = *(const half8*)&PHb[(dh * 16 + lid) * 520 + ks * 32 + quad * 8];
                sacc = __builtin_amdgcn_mfma_f32_16x16x32_f16(thr[ks], bb, sacc, 0, 0, 0);
            }
            __builtin_amdgcn_s_setprio(0);
            const int col = dh * 16 + lid;
            #pragma unroll
            for (int r = 0; r < 4; ++r)
                Ss[(rw * 16 + quad * 4 + r) * 36 + col] = sacc[r] * 1.44269504f;
        }
        // GXb free since last iteration's barrier; gxr issued ~2 phases ago
        #pragma unroll
        for (int i = 0; i < 4; ++i) {
            int idx = t + i * 512;
            *(uint4*)&GXb[(idx >> 2) * 40 + (idx & 3) * 8] = gxr[i];
        }
        bar_lgkm();                                // B1: Ss + GXb visible; PHb reads done

        // ---- phase 2: issue GX[s+1]; wave-parallel softmax ----------------
        if (s < 97) {
            #pragma unroll
            for (int i = 0; i < 4; ++i) {
                int idx = t + i * 512;
                gxr[i] = *(const uint4*)&GXT[baseGX_b + (size_t)(idx >> 2) * N_ + m0n + (idx & 3) * 8];
            }
        }
        {
            float4 s4 = *(const float4*)&Ss[srow * 36 + sj * 4];
            float pm = fmaxf(fmaxf(s4.x, s4.y), fmaxf(s4.z, s4.w));
            pm = fmaxf(pm, __shfl_xor(pm, 1));
            pm = fmaxf(pm, __shfl_xor(pm, 2));
            pm = fmaxf(pm, __shfl_xor(pm, 4));
            const float mo = mrow[srow];
            const float mn = fmaxf(mo, pm);
            const float al = exp2f(mo - mn);
            const float p0 = exp2f(s4.x - mn);
            const float p1 = exp2f(s4.y - mn);
            const float p2 = exp2f(s4.z - mn);
            const float p3 = exp2f(s4.w - mn);
            ushort4 u; u.x = f2h(p0); u.y = f2h(p1); u.z = f2h(p2); u.w = f2h(p3);
            *(ushort4*)&Ps[srow * 40 + sj * 4] = u;
            float ps = p0 + p1 + p2 + p3;
            ps += __shfl_xor(ps, 1);
            ps += __shfl_xor(ps, 2);
            ps += __shfl_xor(ps, 4);
            if (sj == 0) {
                mrow[srow] = mn;
                arow[srow] = al;
                lrow[srow] = lrow[srow] * al + ps;
            }
        }
        bar_lgkm();                                // B2: Ps + m/l/a visible

        // ---- phase 3: rescale (skip if no max growth); O += P*GX; PHb[s+1]
        {
            float al4[4];
            #pragma unroll
            for (int r = 0; r < 4; ++r) al4[r] = arow[rw * 16 + quad * 4 + r];
            const bool need = (al4[0] != 1.f) | (al4[1] != 1.f) | (al4[2] != 1.f) | (al4[3] != 1.f);
            if (__any(need)) {
                #pragma unroll
                for (int ctl = 0; ctl < 16; ++ctl)
                    #pragma unroll
                    for (int r = 0; r < 4; ++r) acc[ctl][r] *= al4[r];
            }
        }
        {
            half8 a = *(const half8*)&Ps[(rw * 16 + lid) * 40 + quad * 8];
            __builtin_amdgcn_s_setprio(1);
            #pragma unroll
            for (int ctl = 0; ctl < 16; ++ctl) {
                half8 bb = *(const half8*)&GXb[(dh * 256 + ctl * 16 + lid) * 40 + quad * 8];
                acc[ctl] = __builtin_amdgcn_mfma_f32_16x16x32_f16(a, bb, acc[ctl], 0, 0, 0);
            }
            __builtin_amdgcn_s_setprio(0);
        }
        if (s < 97) {
            #pragma unroll
            for (int i = 0; i < 4; ++i) {
                int idx = t + i * 512;
                *(uint4*)&PHb[(idx >> 6) * 520 + (idx & 63) * 8] = phr[i];
            }
        }
        bar_lgkm();                                // B3: O reads done; PHb[s+1] visible
    }

    float inv[4];
    #pragma unroll
    for (int r = 0; r < 4; ++r) inv[r] = 1.0f / lrow[rw * 16 + quad * 4 + r];
    const size_t baseY = ((size_t)b * N_ + n0) * CI_;
    #pragma unroll
    for (int ctl = 0; ctl < 16; ++ctl) {
        const int col = dh * 256 + ctl * 16 + lid;
        #pragma unroll
        for (int r = 0; r < 4; ++r) {
            const int row = rw * 16 + quad * 4 + r;
            Y[baseY + (size_t)row * CI_ + col] = f2h(acc[ctl][r] * inv[r]);
        }
    }
}

// ---- BN finalize: scale/shift per channel --------------------------------
__global__ __launch_bounds__(256) void bnfin(const float* __restrict__ ssum, const float* __restrict__ ssq,
                                             const float* __restrict__ gamma, const float* __restrict__ beta,
                                             float* __restrict__ sc) {
    const int c = blockIdx.x * 256 + threadIdx.x;
    const float inv_m = 1.0f / (float)M_;
    const float mu = ssum[c] * inv_m;
    const float var = ssq[c] * inv_m - mu * mu;
    const float s = gamma[c] * rsqrtf(var + BN_EPS);
    sc[c] = s;
    sc[C_ + c] = beta[c] - mu * s;
}

// ---- finalize: out[b][c][n] = wy[b][n][c]*scale+shift + x1[b][c][n] ------
__global__ __launch_bounds__(256) void fin(const ushort* __restrict__ wy, const float* __restrict__ x1,
                                           const float* __restrict__ sc, float* __restrict__ out) {
    __shared__ float T[64 * 65];
    const int b = blockIdx.z, n0 = blockIdx.y * 64, c0 = blockIdx.x * 64;
    const int t = threadIdx.x;
    {
        const int nl = t >> 4, cb = (t & 15) * 4;
        #pragma unroll
        for (int i = 0; i < 4; ++i) {
            int n = nl + i * 16;
            ushort4 u = *(const ushort4*)&wy[((size_t)b * N_ + n0 + n) * C_ + c0 + cb];
            T[(cb + 0) * 65 + n] = h2f(u.x);
            T[(cb + 1) * 65 + n] = h2f(u.y);
            T[(cb + 2) * 65 + n] = h2f(u.z);
            T[(cb + 3) * 65 + n] = h2f(u.w);
        }
    }
    __syncthreads();
    {
        const int cl = t >> 4, nb = (t & 15) * 4;
        #pragma unroll
        for (int i = 0; i < 4; ++i) {
            int c = cl + i * 16;
            const float scale = sc[c0 + c], shift = sc[C_ + c0 + c];
            float4 xv = *(const float4*)&x1[((size_t)b * C_ + c0 + c) * N_ + n0 + nb];
            float4 o;
            o.x = T[c * 65 + nb + 0] * scale + shift + xv.x;
            o.y = T[c * 65 + nb + 1] * scale + shift + xv.y;
            o.z = T[c * 65 + nb + 2] * scale + shift + xv.z;
            o.w = T[c * 65 + nb + 3] * scale + shift + xv.w;
            *(float4*)&out[((size_t)b * C_ + c0 + c) * N_ + n0 + nb] = o;
        }
    }
}

extern "C" void kernel_launch(void* const* d_in, const int* in_sizes, int n_in,
                              void* d_out, int out_size, void* d_ws, size_t ws_size,
                              hipStream_t stream) {
    const float* x1      = (const float*)d_in[0];
    const float* x2      = (const float*)d_in[1];
    const float* g_w     = (const float*)d_in[2];
    const float* g_b     = (const float*)d_in[3];
    const float* theta_w = (const float*)d_in[4];
    const float* theta_b = (const float*)d_in[5];
    const float* phi_w   = (const float*)d_in[6];
    const float* phi_b   = (const float*)d_in[7];
    const float* wz_w    = (const float*)d_in[8];
    const float* wz_b    = (const float*)d_in[9];
    const float* bn_g    = (const float*)d_in[10];
    const float* bn_b    = (const float*)d_in[11];
    float* out = (float*)d_out;

    char* ws = (char*)d_ws;
    ushort* XT1 = (ushort*)(ws + XT1_OFF);
    ushort* XT2 = (ushort*)(ws + XT2_OFF);
    ushort* WTH = (ushort*)(ws + WTH_OFF);
    ushort* WPH = (ushort*)(ws + WPH_OFF);
    ushort* WG  = (ushort*)(ws + WG_OFF);
    ushort* WZB = (ushort*)(ws + WZB_OFF);
    ushort* THp = (ushort*)(ws + TH_OFF);
    ushort* PHp = (ushort*)(ws + PH_OFF);
    ushort* GXTp= (ushort*)(ws + GXT_OFF);
    ushort* Yp  = (ushort*)(ws + Y_OFF);
    ushort* WYp = (ushort*)(ws + WY_OFF);
    float* ssum = (float*)(ws + SSUM_OFF);
    float* ssq  = (float*)(ws + SSQ_OFF);
    float* sc   = (float*)(ws + SC_OFF);

    hipMemsetAsync(ws + SSUM_OFF, 0, 8192, stream);

    cvtw4<<<dim3(512, 4), 256, 0, stream>>>(theta_w, phi_w, g_w, wz_w, WTH, WPH, WG, WZB);
    xpose<<<dim3(16, 49, 8), 256, 0, stream>>>(x1, XT1);
    xpose<<<dim3(16, 49, 8), 256, 0, stream>>>(x2, XT2);

    gemm_bt<1024, 512, 0><<<dim3(4, 196), 256, 0, stream>>>(XT1, WTH, theta_b, THp, nullptr, nullptr);
    gemm_bt<1024, 512, 0><<<dim3(4, 196), 256, 0, stream>>>(XT2, WPH, phi_b, PHp, nullptr, nullptr);
    gemm_bt<1024, 512, 1><<<dim3(4, 196), 256, 0, stream>>>(XT2, WG, g_b, GXTp, nullptr, nullptr);

    attn<<<dim3(B_ * 49), 512, 0, stream>>>(THp, PHp, GXTp, Yp);

    gemm_bt<512, 1024, 2><<<dim3(8, 196), 256, 0, stream>>>(Yp, WZB, wz_b, WYp, ssum, ssq);
    bnfin<<<dim3(4), 256, 0, stream>>>(ssum, ssq, bn_g, bn_b, sc);
    fin<<<dim3(16, 49, 8), 256, 0, stream>>>(WYp, x1, sc, out);
}

// Round 2
// 972.440 us; speedup vs baseline: 1.1765x; 1.1765x over previous
//
#include <hip/hip_runtime.h>

// NLBlockND non-local block, fp16-MFMA implementation (fp16 chosen over bf16:
// scores sigma~22.6 make softmax precision-critical; fp16's 2^-11 roundoff
// keeps score jitter ~0.01 vs bf16's ~0.1).
// Pipeline: cvt weights -> transpose x1/x2 to fp16 (B*N,C) -> 3 proj GEMMs
// (g stored transposed) -> flash attention (online softmax) -> wz GEMM +
// BN stats atomics -> BN finalize -> normalize+residual+transpose out.
//
// attn v3: O-phase split by d across 8 waves (each wave owns 64 d-cols) ->
// GX fragments are per-wave-disjoint, so GX LDS staging is deleted entirely;
// B-fragments load straight from GXT[d][n] (exactly MFMA B layout) into
// registers, issued 2 phases early. Phase-C LDS reads drop 17->9 per wave.
// Dual S-accumulator halves the dependent-MFMA chain. 3 raw barriers/step.

typedef _Float16 half8 __attribute__((ext_vector_type(8)));
typedef float floatx4 __attribute__((ext_vector_type(4)));

constexpr int B_ = 8, C_ = 1024, CI_ = 512, N_ = 3136;
constexpr int M_ = B_ * N_;            // 25088 rows (batch-major, n within batch)
constexpr float BN_EPS = 1e-5f;

// workspace layout (bytes, all 256-aligned)
constexpr size_t XT1_OFF = 0;
constexpr size_t XT2_OFF = XT1_OFF + (size_t)M_ * C_ * 2;
constexpr size_t WTH_OFF = XT2_OFF + (size_t)M_ * C_ * 2;
constexpr size_t WPH_OFF = WTH_OFF + (size_t)CI_ * C_ * 2;
constexpr size_t WG_OFF  = WPH_OFF + (size_t)CI_ * C_ * 2;
constexpr size_t WZB_OFF = WG_OFF  + (size_t)CI_ * C_ * 2;
constexpr size_t TH_OFF  = WZB_OFF + (size_t)C_ * CI_ * 2;
constexpr size_t PH_OFF  = TH_OFF  + (size_t)M_ * CI_ * 2;
constexpr size_t GXT_OFF = PH_OFF  + (size_t)M_ * CI_ * 2;
constexpr size_t Y_OFF   = GXT_OFF + (size_t)M_ * CI_ * 2;
constexpr size_t WY_OFF  = Y_OFF   + (size_t)M_ * CI_ * 2;   // fp16 wy
constexpr size_t SSUM_OFF= WY_OFF  + (size_t)M_ * C_ * 2;
constexpr size_t SSQ_OFF = SSUM_OFF + 4096;
constexpr size_t SC_OFF  = SSQ_OFF + 4096;                    // scale[1024], shift[1024]

__device__ __forceinline__ ushort f2h(float f) {
    _Float16 h = (_Float16)f;
    union { _Float16 h; ushort u; } v; v.h = h;
    return v.u;
}
__device__ __forceinline__ float h2f(ushort u) {
    union { ushort u; _Float16 h; } v; v.u = u;
    return (float)v.h;
}

// raw barrier: waits only LDS ops (lgkmcnt), leaves global prefetch (vmcnt)
// in flight — unlike __syncthreads(), which drains vmcnt(0).
__device__ __forceinline__ void bar_lgkm() {
    asm volatile("s_waitcnt lgkmcnt(0)" ::: "memory");
    __builtin_amdgcn_s_barrier();
}

// ---- weight convert: 4 arrays of 524288 floats -> fp16 -------------------
__global__ __launch_bounds__(256) void cvtw4(const float* __restrict__ a, const float* __restrict__ b,
                                             const float* __restrict__ c, const float* __restrict__ d,
                                             ushort* oa, ushort* ob, ushort* oc, ushort* od) {
    const float* s; ushort* o;
    switch (blockIdx.y) {
        case 0: s = a; o = oa; break;
        case 1: s = b; o = ob; break;
        case 2: s = c; o = oc; break;
        default: s = d; o = od; break;
    }
    int i = (blockIdx.x * 256 + threadIdx.x) * 4;
    float4 v = *(const float4*)&s[i];
    ushort4 u; u.x = f2h(v.x); u.y = f2h(v.y); u.z = f2h(v.z); u.w = f2h(v.w);
    *(ushort4*)&o[i] = u;
}

// ---- transpose x (B,C,N) fp32 -> xt (B*N, C) fp16 ------------------------
__global__ __launch_bounds__(256) void xpose(const float* __restrict__ x, ushort* __restrict__ xt) {
    __shared__ ushort T[64 * 68];
    const int b = blockIdx.z, n0 = blockIdx.y * 64, c0 = blockIdx.x * 64;
    const int t = threadIdx.x;
    {
        const int cl = t >> 4, jb = (t & 15) * 4;
        #pragma unroll
        for (int i = 0; i < 4; ++i) {
            int c = cl + i * 16;
            float4 v = *(const float4*)&x[((size_t)b * C_ + c0 + c) * N_ + n0 + jb];
            ushort4 u; u.x = f2h(v.x); u.y = f2h(v.y); u.z = f2h(v.z); u.w = f2h(v.w);
            *(ushort4*)&T[c * 68 + jb] = u;
        }
    }
    __syncthreads();
    {
        const int nl = t >> 4, cb = (t & 15) * 4;
        #pragma unroll
        for (int i = 0; i < 4; ++i) {
            int n = nl + i * 16;
            ushort4 u;
            u.x = T[(cb + 0) * 68 + n];
            u.y = T[(cb + 1) * 68 + n];
            u.z = T[(cb + 2) * 68 + n];
            u.w = T[(cb + 3) * 68 + n];
            *(ushort4*)&xt[((size_t)b * N_ + n0 + n) * C_ + c0 + cb] = u;
        }
    }
}

// ---- generic 128x128 fp16 MFMA GEMM: out = A(MxK) * Bt(NOUTxK)^T + bias --
// MODE 0: fp16 out row-major (stride NOUT)
// MODE 1: fp16 out transposed per-batch: GXT[b][col][n]  (NOUT==CI_)
// MODE 2: fp16 out row-major + per-col sum/sumsq atomics (BN stats)
template<int K, int NOUT, int MODE>
__global__ __launch_bounds__(256, 2) void gemm_bt(
    const ushort* __restrict__ A, const ushort* __restrict__ Bt,
    const float* __restrict__ bias, ushort* __restrict__ outb,
    float* __restrict__ ssum, float* __restrict__ ssq)
{
    __shared__ ushort Als[128 * 40];
    __shared__ ushort Bls[128 * 40];
    const int t = threadIdx.x;
    const int w = t >> 6, l = t & 63, quad = l >> 4, lid = l & 15;
    const int rw = w & 1, cw = w >> 1;
    const int rowbase = blockIdx.y * 128, colbase = blockIdx.x * 128;

    floatx4 acc[4][4] = {};

    for (int ks = 0; ks < K / 32; ++ks) {
        __syncthreads();
        #pragma unroll
        for (int i = 0; i < 2; ++i) {
            int idx = t + i * 256;
            int row = idx >> 2, ch = idx & 3;
            *(uint4*)&Als[row * 40 + ch * 8] =
                *(const uint4*)&A[(size_t)(rowbase + row) * K + ks * 32 + ch * 8];
            *(uint4*)&Bls[row * 40 + ch * 8] =
                *(const uint4*)&Bt[(size_t)(colbase + row) * K + ks * 32 + ch * 8];
        }
        __syncthreads();
        half8 af[4];
        #pragma unroll
        for (int rt = 0; rt < 4; ++rt)
            af[rt] = *(const half8*)&Als[(rw * 64 + rt * 16 + lid) * 40 + quad * 8];
        #pragma unroll
        for (int ct = 0; ct < 4; ++ct) {
            half8 bf = *(const half8*)&Bls[(cw * 64 + ct * 16 + lid) * 40 + quad * 8];
            #pragma unroll
            for (int rt = 0; rt < 4; ++rt)
                acc[rt][ct] = __builtin_amdgcn_mfma_f32_16x16x32_f16(af[rt], bf, acc[rt][ct], 0, 0, 0);
        }
    }

    #pragma unroll
    for (int ct = 0; ct < 4; ++ct) {
        const int col = colbase + cw * 64 + ct * 16 + lid;
        const float bv = bias[col];
        float s = 0.f, q = 0.f;
        #pragma unroll
        for (int rt = 0; rt < 4; ++rt) {
            const int row0 = rowbase + rw * 64 + rt * 16 + quad * 4;
            if constexpr (MODE == 1) {
                const int bb = row0 / N_;
                const int nn = row0 - bb * N_;
                ushort4 u;
                u.x = f2h(acc[rt][ct][0] + bv);
                u.y = f2h(acc[rt][ct][1] + bv);
                u.z = f2h(acc[rt][ct][2] + bv);
                u.w = f2h(acc[rt][ct][3] + bv);
                *(ushort4*)&outb[((size_t)bb * CI_ + col) * N_ + nn] = u;
            } else {
                #pragma unroll
                for (int r = 0; r < 4; ++r) {
                    float v = acc[rt][ct][r] + bv;
                    outb[(size_t)(row0 + r) * NOUT + col] = f2h(v);
                    if constexpr (MODE == 2) { s += v; q += v * v; }
                }
            }
        }
        if constexpr (MODE == 2) {
            s += __shfl_xor(s, 16, 64); s += __shfl_xor(s, 32, 64);
            q += __shfl_xor(q, 16, 64); q += __shfl_xor(q, 32, 64);
            if (quad == 0) {
                atomicAdd(&ssum[col], s);
                atomicAdd(&ssq[col], q);
            }
        }
    }
}

// ---- flash attention: per block one (batch, 64-row q-tile) ---------------
// Phase A: S = TH*PH^T (waves split 4 q-groups x 2 kv-halves), dual acc.
// Phase B: wave-parallel softmax (8 lanes/row, shfl_xor reduce).
// Phase C: O += P*GX, waves split by d (64 cols each); GX B-frags direct
// from global (GXT[d][n] IS the B-fragment layout), no LDS staging.
__global__ __launch_bounds__(512, 2) void attn(
    const ushort* __restrict__ TH, const ushort* __restrict__ PH,
    const ushort* __restrict__ GXT, ushort* __restrict__ Y)
{
    __shared__ __align__(16) ushort PHb[32 * 520];   // PH tile [32 kv][512 k] (+8 pad)
    __shared__ __align__(16) float  Ss[64 * 36];     // scores*log2e
    __shared__ __align__(16) ushort Ps[64 * 40];     // P tile fp16
    __shared__ __align__(16) float mrow[64];
    __shared__ __align__(16) float lrow[64];
    __shared__ __align__(16) float arow[64];

    const int t = threadIdx.x;
    const int w = t >> 6, l = t & 63, quad = l >> 4, lid = l & 15;
    const int rw = w & 3;                  // S-phase: row group (16 rows)
    const int dh = w >> 2;                 // S-phase: kv half (16 cols)
    const int b = blockIdx.x / 49, q = blockIdx.x % 49;
    const int n0 = q * 64;
    const int srow = t >> 3, sj = t & 7;   // softmax: 8 threads per row

    const size_t basePH_b = (size_t)b * N_ * CI_;
    const size_t baseGX_b = (size_t)b * CI_ * N_;

    // register-cache TH rows for this wave's S tile: rows n0 + rw*16 + lid
    half8 thr[16];
    {
        const size_t baseTH = ((size_t)b * N_ + n0 + rw * 16 + lid) * CI_;
        #pragma unroll
        for (int kc = 0; kc < 16; ++kc)
            thr[kc] = *(const half8*)&TH[baseTH + kc * 32 + quad * 8];
    }
    if (t < 64) { mrow[t] = -1e30f; lrow[t] = 0.f; arow[t] = 1.f; }

    // prologue: stage PH[0] to LDS
    uint4 phr[4];
    #pragma unroll
    for (int i = 0; i < 4; ++i) {
        int idx = t + i * 512;
        phr[i] = *(const uint4*)&PH[basePH_b + (size_t)(idx >> 6) * CI_ + (idx & 63) * 8];
    }
    #pragma unroll
    for (int i = 0; i < 4; ++i) {
        int idx = t + i * 512;
        *(uint4*)&PHb[(idx >> 6) * 520 + (idx & 63) * 8] = phr[i];
    }
    bar_lgkm();                                    // B0: PHb[0] + m/l init visible

    floatx4 acc[4][4] = {};                        // [q-tile][d-tile], wave's 64q x 64d

    for (int s = 0; s < 98; ++s) {
        const int m0 = s * 32, m0n = m0 + 32;

        // ---- phase A: issue GX frags (this step's C) + PH[s+1]; S-MFMA ---
        uint4 gxf[4];
        #pragma unroll
        for (int dt = 0; dt < 4; ++dt)
            gxf[dt] = *(const uint4*)&GXT[baseGX_b + (size_t)(w * 64 + dt * 16 + lid) * N_ + m0 + quad * 8];
        if (s < 97) {
            #pragma unroll
            for (int i = 0; i < 4; ++i) {
                int idx = t + i * 512;
                phr[i] = *(const uint4*)&PH[basePH_b + (size_t)(m0n + (idx >> 6)) * CI_ + (idx & 63) * 8];
            }
        }
        {
            floatx4 s0 = {}, s1 = {};
            __builtin_amdgcn_s_setprio(1);
            #pragma unroll
            for (int ks = 0; ks < 16; ks += 2) {
                half8 b0 = *(const half8*)&PHb[(dh * 16 + lid) * 520 + ks * 32 + quad * 8];
                s0 = __builtin_amdgcn_mfma_f32_16x16x32_f16(thr[ks], b0, s0, 0, 0, 0);
                half8 b1 = *(const half8*)&PHb[(dh * 16 + lid) * 520 + (ks + 1) * 32 + quad * 8];
                s1 = __builtin_amdgcn_mfma_f32_16x16x32_f16(thr[ks + 1], b1, s1, 0, 0, 0);
            }
            __builtin_amdgcn_s_setprio(0);
            const int col = dh * 16 + lid;
            #pragma unroll
            for (int r = 0; r < 4; ++r)
                Ss[(rw * 16 + quad * 4 + r) * 36 + col] = (s0[r] + s1[r]) * 1.44269504f;
        }
        bar_lgkm();                                // B1: Ss visible; PHb reads done

        // ---- phase B: wave-parallel softmax ------------------------------
        {
            float4 s4 = *(const float4*)&Ss[srow * 36 + sj * 4];
            float pm = fmaxf(fmaxf(s4.x, s4.y), fmaxf(s4.z, s4.w));
            pm = fmaxf(pm, __shfl_xor(pm, 1));
            pm = fmaxf(pm, __shfl_xor(pm, 2));
            pm = fmaxf(pm, __shfl_xor(pm, 4));
            const float mo = mrow[srow];
            const float mn = fmaxf(mo, pm);
            const float al = exp2f(mo - mn);
            const float p0 = exp2f(s4.x - mn);
            const float p1 = exp2f(s4.y - mn);
            const float p2 = exp2f(s4.z - mn);
            const float p3 = exp2f(s4.w - mn);
            ushort4 u; u.x = f2h(p0); u.y = f2h(p1); u.z = f2h(p2); u.w = f2h(p3);
            *(ushort4*)&Ps[srow * 40 + sj * 4] = u;
            float ps = p0 + p1 + p2 + p3;
            ps += __shfl_xor(ps, 1);
            ps += __shfl_xor(ps, 2);
            ps += __shfl_xor(ps, 4);
            if (sj == 0) {
                mrow[srow] = mn;
                arow[srow] = al;
                lrow[srow] = lrow[srow] * al + ps;
            }
        }
        bar_lgkm();                                // B2: Ps + m/l/a visible

        // ---- phase C: rescale (skip when stable); O += P*GX; PHb[s+1] ----
        #pragma unroll
        for (int qt = 0; qt < 4; ++qt) {
            float4 al4 = *(const float4*)&arow[qt * 16 + quad * 4];
            const bool need = (al4.x != 1.f) | (al4.y != 1.f) | (al4.z != 1.f) | (al4.w != 1.f);
            if (__any(need)) {
                #pragma unroll
                for (int dt = 0; dt < 4; ++dt) {
                    acc[qt][dt][0] *= al4.x;
                    acc[qt][dt][1] *= al4.y;
                    acc[qt][dt][2] *= al4.z;
                    acc[qt][dt][3] *= al4.w;
                }
            }
        }
        {
            __builtin_amdgcn_s_setprio(1);
            #pragma unroll
            for (int qt = 0; qt < 4; ++qt) {
                half8 a = *(const half8*)&Ps[(qt * 16 + lid) * 40 + quad * 8];
                #pragma unroll
                for (int dt = 0; dt < 4; ++dt) {
                    half8 bv = *(half8*)&gxf[dt];
                    acc[qt][dt] = __builtin_amdgcn_mfma_f32_16x16x32_f16(a, bv, acc[qt][dt], 0, 0, 0);
                }
            }
            __builtin_amdgcn_s_setprio(0);
        }
        if (s < 97) {
            #pragma unroll
            for (int i = 0; i < 4; ++i) {
                int idx = t + i * 512;
                *(uint4*)&PHb[(idx >> 6) * 520 + (idx & 63) * 8] = phr[i];
            }
        }
        bar_lgkm();                                // B3: Ps/arow reads done; PHb[s+1] visible
    }

    const size_t baseY = ((size_t)b * N_ + n0) * CI_;
    #pragma unroll
    for (int qt = 0; qt < 4; ++qt) {
        float4 lr4 = *(const float4*)&lrow[qt * 16 + quad * 4];
        float inv[4] = { 1.f / lr4.x, 1.f / lr4.y, 1.f / lr4.z, 1.f / lr4.w };
        #pragma unroll
        for (int dt = 0; dt < 4; ++dt) {
            const int col = w * 64 + dt * 16 + lid;
            #pragma unroll
            for (int r = 0; r < 4; ++r) {
                const int row = qt * 16 + quad * 4 + r;
                Y[baseY + (size_t)row * CI_ + col] = f2h(acc[qt][dt][r] * inv[r]);
            }
        }
    }
}

// ---- BN finalize: scale/shift per channel --------------------------------
__global__ __launch_bounds__(256) void bnfin(const float* __restrict__ ssum, const float* __restrict__ ssq,
                                             const float* __restrict__ gamma, const float* __restrict__ beta,
                                             float* __restrict__ sc) {
    const int c = blockIdx.x * 256 + threadIdx.x;
    const float inv_m = 1.0f / (float)M_;
    const float mu = ssum[c] * inv_m;
    const float var = ssq[c] * inv_m - mu * mu;
    const float s = gamma[c] * rsqrtf(var + BN_EPS);
    sc[c] = s;
    sc[C_ + c] = beta[c] - mu * s;
}

// ---- finalize: out[b][c][n] = wy[b][n][c]*scale+shift + x1[b][c][n] ------
__global__ __launch_bounds__(256) void fin(const ushort* __restrict__ wy, const float* __restrict__ x1,
                                           const float* __restrict__ sc, float* __restrict__ out) {
    __shared__ float T[64 * 65];
    const int b = blockIdx.z, n0 = blockIdx.y * 64, c0 = blockIdx.x * 64;
    const int t = threadIdx.x;
    {
        const int nl = t >> 4, cb = (t & 15) * 4;
        #pragma unroll
        for (int i = 0; i < 4; ++i) {
            int n = nl + i * 16;
            ushort4 u = *(const ushort4*)&wy[((size_t)b * N_ + n0 + n) * C_ + c0 + cb];
            T[(cb + 0) * 65 + n] = h2f(u.x);
            T[(cb + 1) * 65 + n] = h2f(u.y);
            T[(cb + 2) * 65 + n] = h2f(u.z);
            T[(cb + 3) * 65 + n] = h2f(u.w);
        }
    }
    __syncthreads();
    {
        const int cl = t >> 4, nb = (t & 15) * 4;
        #pragma unroll
        for (int i = 0; i < 4; ++i) {
            int c = cl + i * 16;
            const float scale = sc[c0 + c], shift = sc[C_ + c0 + c];
            float4 xv = *(const float4*)&x1[((size_t)b * C_ + c0 + c) * N_ + n0 + nb];
            float4 o;
            o.x = T[c * 65 + nb + 0] * scale + shift + xv.x;
            o.y = T[c * 65 + nb + 1] * scale + shift + xv.y;
            o.z = T[c * 65 + nb + 2] * scale + shift + xv.z;
            o.w = T[c * 65 + nb + 3] * scale + shift + xv.w;
            *(float4*)&out[((size_t)b * C_ + c0 + c) * N_ + n0 + nb] = o;
        }
    }
}

extern "C" void kernel_launch(void* const* d_in, const int* in_sizes, int n_in,
                              void* d_out, int out_size, void* d_ws, size_t ws_size,
                              hipStream_t stream) {
    const float* x1      = (const float*)d_in[0];
    const float* x2      = (const float*)d_in[1];
    const float* g_w     = (const float*)d_in[2];
    const float* g_b     = (const float*)d_in[3];
    const float* theta_w = (const float*)d_in[4];
    const float* theta_b = (const float*)d_in[5];
    const float* phi_w   = (const float*)d_in[6];
    const float* phi_b   = (const float*)d_in[7];
    const float* wz_w    = (const float*)d_in[8];
    const float* wz_b    = (const float*)d_in[9];
    const float* bn_g    = (const float*)d_in[10];
    const float* bn_b    = (const float*)d_in[11];
    float* out = (float*)d_out;

    char* ws = (char*)d_ws;
    ushort* XT1 = (ushort*)(ws + XT1_OFF);
    ushort* XT2 = (ushort*)(ws + XT2_OFF);
    ushort* WTH = (ushort*)(ws + WTH_OFF);
    ushort* WPH = (ushort*)(ws + WPH_OFF);
    ushort* WG  = (ushort*)(ws + WG_OFF);
    ushort* WZB = (ushort*)(ws + WZB_OFF);
    ushort* THp = (ushort*)(ws + TH_OFF);
    ushort* PHp = (ushort*)(ws + PH_OFF);
    ushort* GXTp= (ushort*)(ws + GXT_OFF);
    ushort* Yp  = (ushort*)(ws + Y_OFF);
    ushort* WYp = (ushort*)(ws + WY_OFF);
    float* ssum = (float*)(ws + SSUM_OFF);
    float* ssq  = (float*)(ws + SSQ_OFF);
    float* sc   = (float*)(ws + SC_OFF);

    hipMemsetAsync(ws + SSUM_OFF, 0, 8192, stream);

    cvtw4<<<dim3(512, 4), 256, 0, stream>>>(theta_w, phi_w, g_w, wz_w, WTH, WPH, WG, WZB);
    xpose<<<dim3(16, 49, 8), 256, 0, stream>>>(x1, XT1);
    xpose<<<dim3(16, 49, 8), 256, 0, stream>>>(x2, XT2);

    gemm_bt<1024, 512, 0><<<dim3(4, 196), 256, 0, stream>>>(XT1, WTH, theta_b, THp, nullptr, nullptr);
    gemm_bt<1024, 512, 0><<<dim3(4, 196), 256, 0, stream>>>(XT2, WPH, phi_b, PHp, nullptr, nullptr);
    gemm_bt<1024, 512, 1><<<dim3(4, 196), 256, 0, stream>>>(XT2, WG, g_b, GXTp, nullptr, nullptr);

    attn<<<dim3(B_ * 49), 512, 0, stream>>>(THp, PHp, GXTp, Yp);

    gemm_bt<512, 1024, 2><<<dim3(8, 196), 256, 0, stream>>>(Yp, WZB, wz_b, WYp, ssum, ssq);
    bnfin<<<dim3(4), 256, 0, stream>>>(ssum, ssq, bn_g, bn_b, sc);
    fin<<<dim3(16, 49, 8), 256, 0, stream>>>(WYp, x1, sc, out);
}

// Round 3
// 903.998 us; speedup vs baseline: 1.2656x; 1.0757x over previous
//
#include <hip/hip_runtime.h>

// NLBlockND non-local block, fp16-MFMA implementation (fp16 chosen over bf16:
// scores sigma~22.6 make softmax precision-critical; fp16's 2^-11 roundoff
// keeps score jitter ~0.01 vs bf16's ~0.1).
// Pipeline: cvt weights -> transpose x1/x2 to fp16 (B*N,C) -> 3 proj GEMMs
// (g stored transposed) -> flash attention (online softmax) -> wz GEMM +
// BN stats atomics -> BN finalize -> normalize+residual+transpose out.
//
// attn v4: KVBLK=64 (was 32) -> 49 steps instead of 98. The kernel is
// latency-bound (per-step fixed cost: 3 barriers + softmax chain + LDS
// round-trips dominates the ~320 MFMA-cycles of work), so doubling work
// per step halves the amortized overhead. Waves: phase A = 4 q-groups x
// 2 kv-halves; phase C = d-split (64 cols/wave), GX B-frags direct from
// global (GXT[d][n] IS the B layout). PH staged via 8-uint4 reg prefetch
// issued one full step early. 3 raw lgkm-barriers/step.

typedef _Float16 half8 __attribute__((ext_vector_type(8)));
typedef float floatx4 __attribute__((ext_vector_type(4)));

constexpr int B_ = 8, C_ = 1024, CI_ = 512, N_ = 3136;
constexpr int M_ = B_ * N_;            // 25088 rows (batch-major, n within batch)
constexpr float BN_EPS = 1e-5f;

// workspace layout (bytes, all 256-aligned)
constexpr size_t XT1_OFF = 0;
constexpr size_t XT2_OFF = XT1_OFF + (size_t)M_ * C_ * 2;
constexpr size_t WTH_OFF = XT2_OFF + (size_t)M_ * C_ * 2;
constexpr size_t WPH_OFF = WTH_OFF + (size_t)CI_ * C_ * 2;
constexpr size_t WG_OFF  = WPH_OFF + (size_t)CI_ * C_ * 2;
constexpr size_t WZB_OFF = WG_OFF  + (size_t)CI_ * C_ * 2;
constexpr size_t TH_OFF  = WZB_OFF + (size_t)C_ * CI_ * 2;
constexpr size_t PH_OFF  = TH_OFF  + (size_t)M_ * CI_ * 2;
constexpr size_t GXT_OFF = PH_OFF  + (size_t)M_ * CI_ * 2;
constexpr size_t Y_OFF   = GXT_OFF + (size_t)M_ * CI_ * 2;
constexpr size_t WY_OFF  = Y_OFF   + (size_t)M_ * CI_ * 2;   // fp16 wy
constexpr size_t SSUM_OFF= WY_OFF  + (size_t)M_ * C_ * 2;
constexpr size_t SSQ_OFF = SSUM_OFF + 4096;
constexpr size_t SC_OFF  = SSQ_OFF + 4096;                    // scale[1024], shift[1024]

__device__ __forceinline__ ushort f2h(float f) {
    _Float16 h = (_Float16)f;
    union { _Float16 h; ushort u; } v; v.h = h;
    return v.u;
}
__device__ __forceinline__ float h2f(ushort u) {
    union { ushort u; _Float16 h; } v; v.u = u;
    return (float)v.h;
}
__device__ __forceinline__ uint pk2h(float a, float b) {
    return (uint)f2h(a) | ((uint)f2h(b) << 16);
}

// raw barrier: waits only LDS ops (lgkmcnt), leaves global prefetch (vmcnt)
// in flight — unlike __syncthreads(), which drains vmcnt(0).
__device__ __forceinline__ void bar_lgkm() {
    asm volatile("s_waitcnt lgkmcnt(0)" ::: "memory");
    __builtin_amdgcn_s_barrier();
}

// ---- weight convert: 4 arrays of 524288 floats -> fp16 -------------------
__global__ __launch_bounds__(256) void cvtw4(const float* __restrict__ a, const float* __restrict__ b,
                                             const float* __restrict__ c, const float* __restrict__ d,
                                             ushort* oa, ushort* ob, ushort* oc, ushort* od) {
    const float* s; ushort* o;
    switch (blockIdx.y) {
        case 0: s = a; o = oa; break;
        case 1: s = b; o = ob; break;
        case 2: s = c; o = oc; break;
        default: s = d; o = od; break;
    }
    int i = (blockIdx.x * 256 + threadIdx.x) * 4;
    float4 v = *(const float4*)&s[i];
    ushort4 u; u.x = f2h(v.x); u.y = f2h(v.y); u.z = f2h(v.z); u.w = f2h(v.w);
    *(ushort4*)&o[i] = u;
}

// ---- transpose x (B,C,N) fp32 -> xt (B*N, C) fp16 ------------------------
__global__ __launch_bounds__(256) void xpose(const float* __restrict__ x, ushort* __restrict__ xt) {
    __shared__ ushort T[64 * 68];
    const int b = blockIdx.z, n0 = blockIdx.y * 64, c0 = blockIdx.x * 64;
    const int t = threadIdx.x;
    {
        const int cl = t >> 4, jb = (t & 15) * 4;
        #pragma unroll
        for (int i = 0; i < 4; ++i) {
            int c = cl + i * 16;
            float4 v = *(const float4*)&x[((size_t)b * C_ + c0 + c) * N_ + n0 + jb];
            ushort4 u; u.x = f2h(v.x); u.y = f2h(v.y); u.z = f2h(v.z); u.w = f2h(v.w);
            *(ushort4*)&T[c * 68 + jb] = u;
        }
    }
    __syncthreads();
    {
        const int nl = t >> 4, cb = (t & 15) * 4;
        #pragma unroll
        for (int i = 0; i < 4; ++i) {
            int n = nl + i * 16;
            ushort4 u;
            u.x = T[(cb + 0) * 68 + n];
            u.y = T[(cb + 1) * 68 + n];
            u.z = T[(cb + 2) * 68 + n];
            u.w = T[(cb + 3) * 68 + n];
            *(ushort4*)&xt[((size_t)b * N_ + n0 + n) * C_ + c0 + cb] = u;
        }
    }
}

// ---- generic 128x128 fp16 MFMA GEMM: out = A(MxK) * Bt(NOUTxK)^T + bias --
// MODE 0: fp16 out row-major (stride NOUT)
// MODE 1: fp16 out transposed per-batch: GXT[b][col][n]  (NOUT==CI_)
// MODE 2: fp16 out row-major + per-col sum/sumsq atomics (BN stats)
template<int K, int NOUT, int MODE>
__global__ __launch_bounds__(256, 2) void gemm_bt(
    const ushort* __restrict__ A, const ushort* __restrict__ Bt,
    const float* __restrict__ bias, ushort* __restrict__ outb,
    float* __restrict__ ssum, float* __restrict__ ssq)
{
    __shared__ ushort Als[128 * 40];
    __shared__ ushort Bls[128 * 40];
    const int t = threadIdx.x;
    const int w = t >> 6, l = t & 63, quad = l >> 4, lid = l & 15;
    const int rw = w & 1, cw = w >> 1;
    const int rowbase = blockIdx.y * 128, colbase = blockIdx.x * 128;

    floatx4 acc[4][4] = {};

    for (int ks = 0; ks < K / 32; ++ks) {
        __syncthreads();
        #pragma unroll
        for (int i = 0; i < 2; ++i) {
            int idx = t + i * 256;
            int row = idx >> 2, ch = idx & 3;
            *(uint4*)&Als[row * 40 + ch * 8] =
                *(const uint4*)&A[(size_t)(rowbase + row) * K + ks * 32 + ch * 8];
            *(uint4*)&Bls[row * 40 + ch * 8] =
                *(const uint4*)&Bt[(size_t)(colbase + row) * K + ks * 32 + ch * 8];
        }
        __syncthreads();
        half8 af[4];
        #pragma unroll
        for (int rt = 0; rt < 4; ++rt)
            af[rt] = *(const half8*)&Als[(rw * 64 + rt * 16 + lid) * 40 + quad * 8];
        #pragma unroll
        for (int ct = 0; ct < 4; ++ct) {
            half8 bf = *(const half8*)&Bls[(cw * 64 + ct * 16 + lid) * 40 + quad * 8];
            #pragma unroll
            for (int rt = 0; rt < 4; ++rt)
                acc[rt][ct] = __builtin_amdgcn_mfma_f32_16x16x32_f16(af[rt], bf, acc[rt][ct], 0, 0, 0);
        }
    }

    #pragma unroll
    for (int ct = 0; ct < 4; ++ct) {
        const int col = colbase + cw * 64 + ct * 16 + lid;
        const float bv = bias[col];
        float s = 0.f, q = 0.f;
        #pragma unroll
        for (int rt = 0; rt < 4; ++rt) {
            const int row0 = rowbase + rw * 64 + rt * 16 + quad * 4;
            if constexpr (MODE == 1) {
                const int bb = row0 / N_;
                const int nn = row0 - bb * N_;
                ushort4 u;
                u.x = f2h(acc[rt][ct][0] + bv);
                u.y = f2h(acc[rt][ct][1] + bv);
                u.z = f2h(acc[rt][ct][2] + bv);
                u.w = f2h(acc[rt][ct][3] + bv);
                *(ushort4*)&outb[((size_t)bb * CI_ + col) * N_ + nn] = u;
            } else {
                #pragma unroll
                for (int r = 0; r < 4; ++r) {
                    float v = acc[rt][ct][r] + bv;
                    outb[(size_t)(row0 + r) * NOUT + col] = f2h(v);
                    if constexpr (MODE == 2) { s += v; q += v * v; }
                }
            }
        }
        if constexpr (MODE == 2) {
            s += __shfl_xor(s, 16, 64); s += __shfl_xor(s, 32, 64);
            q += __shfl_xor(q, 16, 64); q += __shfl_xor(q, 32, 64);
            if (quad == 0) {
                atomicAdd(&ssum[col], s);
                atomicAdd(&ssq[col], q);
            }
        }
    }
}

// ---- flash attention: per block one (batch, 64-row q-tile), KVBLK=64 -----
// Phase A: S = TH*PH^T (waves: 4 q-groups x 2 kv-halves), dual acc per
//          kv-subtile. Phase B: wave-parallel softmax (8 lanes/row over 64
//          cols). Phase C: O += P*GX, waves split by d (64 cols each), GX
//          B-frags direct from global. 3 raw barriers per 64-kv step.
__global__ __launch_bounds__(512, 2) void attn(
    const ushort* __restrict__ TH, const ushort* __restrict__ PH,
    const ushort* __restrict__ GXT, ushort* __restrict__ Y)
{
    __shared__ __align__(16) ushort PHb[64 * 520];   // PH tile [64 kv][512 k] (+8 pad) 66.5 KB
    __shared__ __align__(16) float  Ss[64 * 68];     // scores*log2e; stride 68: f4-aligned, 2-way write
    __shared__ __align__(16) ushort Ps[64 * 72];     // P tile fp16; stride 72 (144 B)
    __shared__ __align__(16) float mrow[64];
    __shared__ __align__(16) float lrow[64];
    __shared__ __align__(16) float arow[64];

    const int t = threadIdx.x;
    const int w = t >> 6, l = t & 63, quad = l >> 4, lid = l & 15;
    const int rw = w & 3;                  // S-phase: q group (16 rows)
    const int kh = w >> 2;                 // S-phase: kv half (32 cols)
    const int b = blockIdx.x / 49, q = blockIdx.x % 49;
    const int n0 = q * 64;
    const int srow = t >> 3, sj = t & 7;   // softmax: 8 threads per row

    const size_t basePH_b = (size_t)b * N_ * CI_;
    const size_t baseGX_b = (size_t)b * CI_ * N_;

    // register-cache TH rows for this wave's S tile: rows n0 + rw*16 + lid
    half8 thr[16];
    {
        const size_t baseTH = ((size_t)b * N_ + n0 + rw * 16 + lid) * CI_;
        #pragma unroll
        for (int kc = 0; kc < 16; ++kc)
            thr[kc] = *(const half8*)&TH[baseTH + kc * 32 + quad * 8];
    }
    if (t < 64) { mrow[t] = -1e30f; lrow[t] = 0.f; arow[t] = 1.f; }

    // prologue: stage PH[0] (64 rows x 512 k) to LDS
    uint4 phr[8];
    #pragma unroll
    for (int i = 0; i < 8; ++i) {
        int idx = t + i * 512;
        phr[i] = *(const uint4*)&PH[basePH_b + (size_t)(idx >> 6) * CI_ + (idx & 63) * 8];
    }
    #pragma unroll
    for (int i = 0; i < 8; ++i) {
        int idx = t + i * 512;
        *(uint4*)&PHb[(idx >> 6) * 520 + (idx & 63) * 8] = phr[i];
    }
    bar_lgkm();                                    // B0: PHb[0] + m/l init visible

    floatx4 acc[4][4] = {};                        // [q-tile][d-tile], wave's 64q x 64d

    for (int s = 0; s < 49; ++s) {
        const int m0 = s * 64, m0n = m0 + 64;

        // ---- phase A: issue GX frags (this step) + PH[s+1]; S-MFMA -------
        uint4 gxf[8];                              // [dt][ks]
        #pragma unroll
        for (int dt = 0; dt < 4; ++dt)
            #pragma unroll
            for (int ks = 0; ks < 2; ++ks)
                gxf[dt * 2 + ks] = *(const uint4*)&GXT[baseGX_b +
                    (size_t)(w * 64 + dt * 16 + lid) * N_ + m0 + ks * 32 + quad * 8];
        if (s < 48) {
            #pragma unroll
            for (int i = 0; i < 8; ++i) {
                int idx = t + i * 512;
                phr[i] = *(const uint4*)&PH[basePH_b + (size_t)(m0n + (idx >> 6)) * CI_ + (idx & 63) * 8];
            }
        }
        __builtin_amdgcn_s_setprio(1);
        #pragma unroll
        for (int ct = 0; ct < 2; ++ct) {
            floatx4 s0 = {}, s1 = {};
            const int rbase = (kh * 32 + ct * 16 + lid) * 520;
            #pragma unroll
            for (int ks = 0; ks < 16; ks += 2) {
                half8 b0 = *(const half8*)&PHb[rbase + ks * 32 + quad * 8];
                s0 = __builtin_amdgcn_mfma_f32_16x16x32_f16(thr[ks], b0, s0, 0, 0, 0);
                half8 b1 = *(const half8*)&PHb[rbase + (ks + 1) * 32 + quad * 8];
                s1 = __builtin_amdgcn_mfma_f32_16x16x32_f16(thr[ks + 1], b1, s1, 0, 0, 0);
            }
            const int col = kh * 32 + ct * 16 + lid;
            #pragma unroll
            for (int r = 0; r < 4; ++r)
                Ss[(rw * 16 + quad * 4 + r) * 68 + col] = (s0[r] + s1[r]) * 1.44269504f;
        }
        __builtin_amdgcn_s_setprio(0);
        bar_lgkm();                                // B1: Ss visible; PHb reads done

        // ---- phase B: wave-parallel softmax over 64 cols -----------------
        {
            float4 sa = *(const float4*)&Ss[srow * 68 + sj * 8];
            float4 sb = *(const float4*)&Ss[srow * 68 + sj * 8 + 4];
            float pm = fmaxf(fmaxf(fmaxf(sa.x, sa.y), fmaxf(sa.z, sa.w)),
                             fmaxf(fmaxf(sb.x, sb.y), fmaxf(sb.z, sb.w)));
            pm = fmaxf(pm, __shfl_xor(pm, 1));
            pm = fmaxf(pm, __shfl_xor(pm, 2));
            pm = fmaxf(pm, __shfl_xor(pm, 4));
            const float mo = mrow[srow];
            const float mn = fmaxf(mo, pm);
            const float al = exp2f(mo - mn);
            const float p0 = exp2f(sa.x - mn), p1 = exp2f(sa.y - mn);
            const float p2 = exp2f(sa.z - mn), p3 = exp2f(sa.w - mn);
            const float p4 = exp2f(sb.x - mn), p5 = exp2f(sb.y - mn);
            const float p6 = exp2f(sb.z - mn), p7 = exp2f(sb.w - mn);
            uint4 pk;
            pk.x = pk2h(p0, p1); pk.y = pk2h(p2, p3);
            pk.z = pk2h(p4, p5); pk.w = pk2h(p6, p7);
            *(uint4*)&Ps[srow * 72 + sj * 8] = pk;
            float ps = ((p0 + p1) + (p2 + p3)) + ((p4 + p5) + (p6 + p7));
            ps += __shfl_xor(ps, 1);
            ps += __shfl_xor(ps, 2);
            ps += __shfl_xor(ps, 4);
            if (sj == 0) {
                mrow[srow] = mn;
                arow[srow] = al;
                lrow[srow] = lrow[srow] * al + ps;
            }
        }
        bar_lgkm();                                // B2: Ps + m/l/a visible

        // ---- phase C: rescale (skip when stable); O += P*GX; PHb[s+1] ----
        #pragma unroll
        for (int qt = 0; qt < 4; ++qt) {
            float4 al4 = *(const float4*)&arow[qt * 16 + quad * 4];
            const bool need = (al4.x != 1.f) | (al4.y != 1.f) | (al4.z != 1.f) | (al4.w != 1.f);
            if (__any(need)) {
                #pragma unroll
                for (int dt = 0; dt < 4; ++dt) {
                    acc[qt][dt][0] *= al4.x;
                    acc[qt][dt][1] *= al4.y;
                    acc[qt][dt][2] *= al4.z;
                    acc[qt][dt][3] *= al4.w;
                }
            }
        }
        __builtin_amdgcn_s_setprio(1);
        #pragma unroll
        for (int qt = 0; qt < 4; ++qt) {
            #pragma unroll
            for (int ks = 0; ks < 2; ++ks) {
                half8 a = *(const half8*)&Ps[(qt * 16 + lid) * 72 + ks * 32 + quad * 8];
                #pragma unroll
                for (int dt = 0; dt < 4; ++dt) {
                    half8 bv = *(half8*)&gxf[dt * 2 + ks];
                    acc[qt][dt] = __builtin_amdgcn_mfma_f32_16x16x32_f16(a, bv, acc[qt][dt], 0, 0, 0);
                }
            }
        }
        __builtin_amdgcn_s_setprio(0);
        if (s < 48) {
            #pragma unroll
            for (int i = 0; i < 8; ++i) {
                int idx = t + i * 512;
                *(uint4*)&PHb[(idx >> 6) * 520 + (idx & 63) * 8] = phr[i];
            }
        }
        bar_lgkm();                                // B3: Ps/arow reads done; PHb[s+1] visible
    }

    const size_t baseY = ((size_t)b * N_ + n0) * CI_;
    #pragma unroll
    for (int qt = 0; qt < 4; ++qt) {
        float4 lr4 = *(const float4*)&lrow[qt * 16 + quad * 4];
        float inv[4] = { 1.f / lr4.x, 1.f / lr4.y, 1.f / lr4.z, 1.f / lr4.w };
        #pragma unroll
        for (int dt = 0; dt < 4; ++dt) {
            const int col = w * 64 + dt * 16 + lid;
            #pragma unroll
            for (int r = 0; r < 4; ++r) {
                const int row = qt * 16 + quad * 4 + r;
                Y[baseY + (size_t)row * CI_ + col] = f2h(acc[qt][dt][r] * inv[r]);
            }
        }
    }
}

// ---- BN finalize: scale/shift per channel --------------------------------
__global__ __launch_bounds__(256) void bnfin(const float* __restrict__ ssum, const float* __restrict__ ssq,
                                             const float* __restrict__ gamma, const float* __restrict__ beta,
                                             float* __restrict__ sc) {
    const int c = blockIdx.x * 256 + threadIdx.x;
    const float inv_m = 1.0f / (float)M_;
    const float mu = ssum[c] * inv_m;
    const float var = ssq[c] * inv_m - mu * mu;
    const float s = gamma[c] * rsqrtf(var + BN_EPS);
    sc[c] = s;
    sc[C_ + c] = beta[c] - mu * s;
}

// ---- finalize: out[b][c][n] = wy[b][n][c]*scale+shift + x1[b][c][n] ------
__global__ __launch_bounds__(256) void fin(const ushort* __restrict__ wy, const float* __restrict__ x1,
                                           const float* __restrict__ sc, float* __restrict__ out) {
    __shared__ float T[64 * 65];
    const int b = blockIdx.z, n0 = blockIdx.y * 64, c0 = blockIdx.x * 64;
    const int t = threadIdx.x;
    {
        const int nl = t >> 4, cb = (t & 15) * 4;
        #pragma unroll
        for (int i = 0; i < 4; ++i) {
            int n = nl + i * 16;
            ushort4 u = *(const ushort4*)&wy[((size_t)b * N_ + n0 + n) * C_ + c0 + cb];
            T[(cb + 0) * 65 + n] = h2f(u.x);
            T[(cb + 1) * 65 + n] = h2f(u.y);
            T[(cb + 2) * 65 + n] = h2f(u.z);
            T[(cb + 3) * 65 + n] = h2f(u.w);
        }
    }
    __syncthreads();
    {
        const int cl = t >> 4, nb = (t & 15) * 4;
        #pragma unroll
        for (int i = 0; i < 4; ++i) {
            int c = cl + i * 16;
            const float scale = sc[c0 + c], shift = sc[C_ + c0 + c];
            float4 xv = *(const float4*)&x1[((size_t)b * C_ + c0 + c) * N_ + n0 + nb];
            float4 o;
            o.x = T[c * 65 + nb + 0] * scale + shift + xv.x;
            o.y = T[c * 65 + nb + 1] * scale + shift + xv.y;
            o.z = T[c * 65 + nb + 2] * scale + shift + xv.z;
            o.w = T[c * 65 + nb + 3] * scale + shift + xv.w;
            *(float4*)&out[((size_t)b * C_ + c0 + c) * N_ + n0 + nb] = o;
        }
    }
}

extern "C" void kernel_launch(void* const* d_in, const int* in_sizes, int n_in,
                              void* d_out, int out_size, void* d_ws, size_t ws_size,
                              hipStream_t stream) {
    const float* x1      = (const float*)d_in[0];
    const float* x2      = (const float*)d_in[1];
    const float* g_w     = (const float*)d_in[2];
    const float* g_b     = (const float*)d_in[3];
    const float* theta_w = (const float*)d_in[4];
    const float* theta_b = (const float*)d_in[5];
    const float* phi_w   = (const float*)d_in[6];
    const float* phi_b   = (const float*)d_in[7];
    const float* wz_w    = (const float*)d_in[8];
    const float* wz_b    = (const float*)d_in[9];
    const float* bn_g    = (const float*)d_in[10];
    const float* bn_b    = (const float*)d_in[11];
    float* out = (float*)d_out;

    char* ws = (char*)d_ws;
    ushort* XT1 = (ushort*)(ws + XT1_OFF);
    ushort* XT2 = (ushort*)(ws + XT2_OFF);
    ushort* WTH = (ushort*)(ws + WTH_OFF);
    ushort* WPH = (ushort*)(ws + WPH_OFF);
    ushort* WG  = (ushort*)(ws + WG_OFF);
    ushort* WZB = (ushort*)(ws + WZB_OFF);
    ushort* THp = (ushort*)(ws + TH_OFF);
    ushort* PHp = (ushort*)(ws + PH_OFF);
    ushort* GXTp= (ushort*)(ws + GXT_OFF);
    ushort* Yp  = (ushort*)(ws + Y_OFF);
    ushort* WYp = (ushort*)(ws + WY_OFF);
    float* ssum = (float*)(ws + SSUM_OFF);
    float* ssq  = (float*)(ws + SSQ_OFF);
    float* sc   = (float*)(ws + SC_OFF);

    hipMemsetAsync(ws + SSUM_OFF, 0, 8192, stream);

    cvtw4<<<dim3(512, 4), 256, 0, stream>>>(theta_w, phi_w, g_w, wz_w, WTH, WPH, WG, WZB);
    xpose<<<dim3(16, 49, 8), 256, 0, stream>>>(x1, XT1);
    xpose<<<dim3(16, 49, 8), 256, 0, stream>>>(x2, XT2);

    gemm_bt<1024, 512, 0><<<dim3(4, 196), 256, 0, stream>>>(XT1, WTH, theta_b, THp, nullptr, nullptr);
    gemm_bt<1024, 512, 0><<<dim3(4, 196), 256, 0, stream>>>(XT2, WPH, phi_b, PHp, nullptr, nullptr);
    gemm_bt<1024, 512, 1><<<dim3(4, 196), 256, 0, stream>>>(XT2, WG, g_b, GXTp, nullptr, nullptr);

    attn<<<dim3(B_ * 49), 512, 0, stream>>>(THp, PHp, GXTp, Yp);

    gemm_bt<512, 1024, 2><<<dim3(8, 196), 256, 0, stream>>>(Yp, WZB, wz_b, WYp, ssum, ssq);
    bnfin<<<dim3(4), 256, 0, stream>>>(ssum, ssq, bn_g, bn_b, sc);
    fin<<<dim3(16, 49, 8), 256, 0, stream>>>(WYp, x1, sc, out);
}